// Round 5
// baseline (364.504 us; speedup 1.0000x reference)
//
#include <hip/hip_runtime.h>
#include <hip/hip_bf16.h>
#include <cstdint>

#define BATCH   4096
#define IN_DIM  1024
#define OUT_DIM 1024
#define NEXP    16

typedef __bf16 bf16;
typedef __attribute__((ext_vector_type(8))) __bf16 bf16x8;
typedef __attribute__((ext_vector_type(4))) float  f32x4;

#define AS1 __attribute__((address_space(1)))
#define AS3 __attribute__((address_space(3)))

__device__ __forceinline__ void gld_lds16(const bf16* g, bf16* l) {
    __builtin_amdgcn_global_load_lds((const AS1 void*)g, (AS3 void*)l, 16, 0, 0);
}

// ---------------------------------------------------------------------------
// Merged conversion kernel (unchanged — proven clean).
// Blocks [0,4096): weight fp32 -> fragment-ordered bf16 tiles via LDS
//   transpose (coalesced f32x4 row reads).
// Blocks [4096,4608): x fp32 -> 512 pre-tiled swizzled bf16 images.
// ---------------------------------------------------------------------------
__global__ __launch_bounds__(256) void convert_all(
        const float* __restrict__ x, const float* __restrict__ W,
        bf16* __restrict__ xt, bf16* __restrict__ wt) {
    __shared__ float Ls[64][65];       // pad 65: read phase is 2-way (free)
    int t = threadIdx.x;
    int bid = blockIdx.x;
    if (bid < 4096) {
        int nblk = bid >> 8, ne = (bid >> 4) & 15, ks = bid & 15;
        int kb = ne * 1024 + ks * 64;
        int n0 = nblk * 64;
#pragma unroll
        for (int r = 0; r < 4; r++) {
            int idx = r * 256 + t;             // 1024 f32x4 = 64x64 tile
            int row = idx >> 4, c4 = (idx & 15) * 4;
            f32x4 v = *(const f32x4*)(W + (size_t)(kb + row) * OUT_DIM + n0 + c4);
#pragma unroll
            for (int j = 0; j < 4; j++) Ls[row][c4 + j] = v[j];
        }
        __syncthreads();
#pragma unroll
        for (int r = 0; r < 2; r++) {
            int c = r * 256 + t;               // 0..511
            int sub = c >> 6, l = c & 63;
            int lr = l & 15, lq = l >> 4;
            int kk = sub >> 2, wn = (sub >> 1) & 1, nt = sub & 1;
            int krow = kk * 32 + lq * 8;
            int col = wn * 32 + nt * 16 + lr;
            bf16x8 v;
#pragma unroll
            for (int j = 0; j < 8; j++) v[j] = (bf16)Ls[krow + j][col];
            *(bf16x8*)(wt + (size_t)bid * 4096 + c * 8) = v;
        }
    } else {
        int tile = bid - 4096;                 // 512
        int mblk = tile >> 4, ks = tile & 15;
#pragma unroll
        for (int r = 0; r < 4; r++) {
            int q = r * 256 + t;
            int m_loc = q >> 3, sc = q & 7;
            int cc = sc ^ (m_loc & 7);
            const float* src = x + (size_t)(mblk * 128 + m_loc) * IN_DIM + ks * 64 + cc * 8;
            f32x4 a = *(const f32x4*)src;
            f32x4 b = *(const f32x4*)(src + 4);
            bf16x8 v;
#pragma unroll
            for (int j = 0; j < 4; j++) { v[j] = (bf16)a[j]; v[4 + j] = (bf16)b[j]; }
            *(bf16x8*)(xt + (size_t)tile * 8192 + q * 8) = v;
        }
    }
}

// ---------------------------------------------------------------------------
// GEMM, TRANSPOSED compute: p = mfma(B_frag, A_frag, ·) gives D = (x·W)^T,
// i.e. D row-quad = output column, D col (lane&15) = batch row. Identical
// LDS images and fragment reads as before (A/B frag layouts are mutual
// transposes). Why: the combine scale cw[b][ne] now depends only on lane&15
// -> ONE scalar VGPR per (mt, ne), preloaded once (64 VGPRs), killing the
// 512 ds_read/CU/ks of scale traffic (47% of the LDS-pipe load; the kernel
// is LDS-pipe-bound at ~87 us busy vs 62 us MFMA). Expert loop fully
// unrolled so sreg[mt][ne>>2][ne&3] is compile-time (rule #20).
// Epilogue bonus: each lane's 4 acc floats are 4 consecutive out columns ->
// one global_store_dwordx4. cwT LDS removed entirely.
// Loop/barrier shape = R4's proven-clean: 4 B-buffers, prefetch pair
// {ne+2,ne+3} before computing pair {ne,ne+1}, __syncthreads per pair.
// Block 128m x 64n, 4 waves (2x2), wave tile 64x32, mfma 16x16x32 bf16.
// LDS 48 KB; grid 512 = 2 blocks/CU (grid-limited).
// ---------------------------------------------------------------------------
__global__ __launch_bounds__(256, 2) void moe_gemm(
        const float* __restrict__ cw, const float* __restrict__ bias,
        const bf16* __restrict__ xt, const bf16* __restrict__ wt,
        float* __restrict__ out) {
    int nblk = blockIdx.x;                 // 16 -> bid%8 clusters nblk per XCD
    int mblk = blockIdx.y;                 // 32
    int m0 = mblk * 128, n0 = nblk * 64;
    int t = threadIdx.x;
    int lane = t & 63, w = t >> 6;
    int wm = w >> 1, wn = w & 1;
    int lq = lane >> 4, lr = lane & 15;

    __shared__ bf16 As[128 * 64];          // 16 KB swizzled A image
    __shared__ bf16 Bs[4][64 * 64];        // 4 x 8 KB fragment-ordered B tiles

    // ---- scale file: 64 VGPRs. sreg[mt][g][c] = cw[row(mt)][g*4+c], where
    //      row(mt) = m0 + wm*64 + mt*16 + lr  (the lane's batch row in the
    //      transposed C/D layout). Loaded once; indices all compile-time.
    f32x4 sreg[4][4];
#pragma unroll
    for (int mt = 0; mt < 4; mt++) {
        const f32x4* p = (const f32x4*)(cw + (size_t)(m0 + wm * 64 + mt * 16 + lr) * NEXP);
#pragma unroll
        for (int g = 0; g < 4; g++) sreg[mt][g] = p[g];
    }

    const f32x4 fz = {0.f, 0.f, 0.f, 0.f};
    f32x4 acc[4][2];
#pragma unroll
    for (int mt = 0; mt < 4; mt++)
#pragma unroll
        for (int nt = 0; nt < 2; nt++) acc[mt][nt] = fz;

    int swz = lr & 7;
    int mrow[4];
#pragma unroll
    for (int mt = 0; mt < 4; mt++) mrow[mt] = (wm * 64 + mt * 16 + lr) * 64;

    const bf16* abase = xt + (size_t)(mblk * 16) * 8192;
    const bf16* bbase = wt + (size_t)nblk * (16 * 16 * 4096);

#pragma unroll 1
    for (int ks = 0; ks < 16; ks++) {
        // stage A tile (16 KB) + B tiles for ne=0,1; one drain barrier
        const bf16* asrc = abase + (size_t)ks * 8192 + t * 8;
#pragma unroll
        for (int r = 0; r < 4; r++) gld_lds16(asrc + r * 2048, &As[r * 2048 + t * 8]);
        const bf16* b0 = bbase + (size_t)ks * 4096 + t * 8;          // ne = 0
        gld_lds16(b0,        &Bs[0][t * 8]);
        gld_lds16(b0 + 2048, &Bs[0][2048 + t * 8]);
        const bf16* b1 = bbase + (size_t)(16 + ks) * 4096 + t * 8;   // ne = 1
        gld_lds16(b1,        &Bs[1][t * 8]);
        gld_lds16(b1 + 2048, &Bs[1][2048 + t * 8]);
        __syncthreads();

        // A fragments -> registers, reused across all 16 experts
        bf16x8 af[4][2];
#pragma unroll
        for (int kk = 0; kk < 2; kk++)
#pragma unroll
            for (int mt = 0; mt < 4; mt++)
                af[mt][kk] = *(const bf16x8*)&As[mrow[mt] + ((kk * 4 + lq) ^ swz) * 8];

#pragma unroll
        for (int ne = 0; ne < 16; ne++) {
            if ((ne & 1) == 0 && ne < 14) {    // prefetch pair {ne+2, ne+3}
                const bf16* bn2 = bbase + (size_t)((ne + 2) * 16 + ks) * 4096 + t * 8;
                bf16* bd2 = &Bs[(ne + 2) & 3][t * 8];
                gld_lds16(bn2,        bd2);
                gld_lds16(bn2 + 2048, bd2 + 2048);
                const bf16* bn3 = bbase + (size_t)((ne + 3) * 16 + ks) * 4096 + t * 8;
                bf16* bd3 = &Bs[(ne + 3) & 3][t * 8];
                gld_lds16(bn3,        bd3);
                gld_lds16(bn3 + 2048, bd3 + 2048);
            }
            // B fragments (linear, conflict-free)
            bf16x8 bfr[2][2];
#pragma unroll
            for (int kk = 0; kk < 2; kk++)
#pragma unroll
                for (int nt = 0; nt < 2; nt++)
                    bfr[kk][nt] = *(const bf16x8*)
                        &Bs[ne & 3][((kk * 2 + wn) * 2 + nt) * 512 + lane * 8];
            // MFMA (swapped operands -> transposed D) + scalar-scale fold
#pragma unroll
            for (int mt = 0; mt < 4; mt++) {
                float sv = sreg[mt][ne >> 2][ne & 3];   // compile-time extract
#pragma unroll
                for (int nt = 0; nt < 2; nt++) {
                    f32x4 p = __builtin_amdgcn_mfma_f32_16x16x32_bf16(
                        bfr[0][nt], af[mt][0], fz, 0, 0, 0);
                    p = __builtin_amdgcn_mfma_f32_16x16x32_bf16(
                        bfr[1][nt], af[mt][1], p, 0, 0, 0);
                    acc[mt][nt] += sv * p;              // scalar x f32x4 fmac
                }
            }
            if (ne & 1) __syncthreads();       // barrier per expert pair
        }
    }

    // ---- bias: one MFMA k-step (k = ne), swapped operands like the body ----
    {
        bf16x8 acw[4];
#pragma unroll
        for (int mt = 0; mt < 4; mt++) {
            bf16x8 v;
#pragma unroll
            for (int j = 0; j < 8; j++) v[j] = (bf16)0.f;
            if (lq < 2) {                  // k = lq*8+j in 0..15 real, else 0
                int row = m0 + wm * 64 + mt * 16 + lr;
                f32x4 a = *(const f32x4*)(cw + (size_t)row * NEXP + lq * 8);
                f32x4 b = *(const f32x4*)(cw + (size_t)row * NEXP + lq * 8 + 4);
#pragma unroll
                for (int j = 0; j < 4; j++) { v[j] = (bf16)a[j]; v[4 + j] = (bf16)b[j]; }
            }
            acw[mt] = v;
        }
        bf16x8 bb[2];
#pragma unroll
        for (int nt = 0; nt < 2; nt++) {
            bf16x8 v;
#pragma unroll
            for (int j = 0; j < 8; j++) v[j] = (bf16)0.f;
            if (lq < 2) {
                int col = n0 + wn * 32 + nt * 16 + lr;
#pragma unroll
                for (int j = 0; j < 8; j++)
                    v[j] = (bf16)bias[(size_t)(lq * 8 + j) * OUT_DIM + col];
            }
            bb[nt] = v;
        }
#pragma unroll
        for (int mt = 0; mt < 4; mt++)
#pragma unroll
            for (int nt = 0; nt < 2; nt++)
                acc[mt][nt] = __builtin_amdgcn_mfma_f32_16x16x32_bf16(
                    bb[nt], acw[mt], acc[mt][nt], 0, 0, 0);
    }

    // epilogue: relu + store. Transposed C/D: lane's 4 acc floats are 4
    // CONSECUTIVE output columns -> one dwordx4 store per (mt,nt).
    //   row = m0 + wm*64 + mt*16 + lr;  col = n0 + wn*32 + nt*16 + lq*4 + r2
#pragma unroll
    for (int mt = 0; mt < 4; mt++) {
        int row = m0 + wm * 64 + mt * 16 + lr;
#pragma unroll
        for (int nt = 0; nt < 2; nt++) {
            int col = n0 + wn * 32 + nt * 16 + lq * 4;
            f32x4 v = acc[mt][nt];
#pragma unroll
            for (int r2 = 0; r2 < 4; r2++) v[r2] = v[r2] > 0.f ? v[r2] : 0.f;
            *(f32x4*)(out + (size_t)row * OUT_DIM + col) = v;
        }
    }
}

// ---------------------------------------------------------------------------
// Insurance fallback if ws_size is too small.
// ---------------------------------------------------------------------------
__global__ void fallback_kernel(const float* __restrict__ x, const float* __restrict__ cw,
                                const float* __restrict__ W, const float* __restrict__ bias,
                                float* __restrict__ out) {
    int o = blockIdx.x * 256 + threadIdx.x;
    int b = o >> 10, oc = o & 1023;
    const float* xr = x + (size_t)b * IN_DIM;
    float accv = 0.f;
    for (int n = 0; n < NEXP; n++) {
        const float* wr = W + (size_t)n * IN_DIM * OUT_DIM + oc;
        float z = 0.f;
        for (int i = 0; i < IN_DIM; i++) z += xr[i] * wr[(size_t)i * OUT_DIM];
        accv += cw[(size_t)b * NEXP + n] * (z + bias[n * OUT_DIM + oc]);
    }
    out[o] = accv > 0.f ? accv : 0.f;
}

extern "C" void kernel_launch(void* const* d_in, const int* in_sizes, int n_in,
                              void* d_out, int out_size, void* d_ws, size_t ws_size,
                              hipStream_t stream) {
    const float* x    = (const float*)d_in[0];
    const float* cw   = (const float*)d_in[1];
    const float* W    = (const float*)d_in[2];
    const float* bias = (const float*)d_in[3];
    float* out = (float*)d_out;

    const size_t wt_elems = (size_t)NEXP * IN_DIM * OUT_DIM;   // 32 MB bf16
    const size_t xt_elems = (size_t)BATCH * IN_DIM;            // 8 MB bf16
    if (ws_size < (wt_elems + xt_elems) * sizeof(bf16)) {
        fallback_kernel<<<(BATCH * OUT_DIM) / 256, 256, 0, stream>>>(x, cw, W, bias, out);
        return;
    }
    bf16* wt = (bf16*)d_ws;
    bf16* xt = wt + wt_elems;

    convert_all<<<4096 + 512, 256, 0, stream>>>(x, W, xt, wt);
    moe_gemm<<<dim3(16, 32), 256, 0, stream>>>(cw, bias, xt, wt, out);
}

// Round 7
// 242.739 us; speedup vs baseline: 1.5016x; 1.5016x over previous
//
#include <hip/hip_runtime.h>
#include <hip/hip_bf16.h>
#include <cstdint>

#define BATCH   4096
#define IN_DIM  1024
#define OUT_DIM 1024
#define NEXP    16

typedef __bf16 bf16;
typedef __attribute__((ext_vector_type(8))) __bf16 bf16x8;
typedef __attribute__((ext_vector_type(4))) float  f32x4;

#define AS1 __attribute__((address_space(1)))
#define AS3 __attribute__((address_space(3)))

__device__ __forceinline__ void gld_lds16(const bf16* g, bf16* l) {
    __builtin_amdgcn_global_load_lds((const AS1 void*)g, (AS3 void*)l, 16, 0, 0);
}

// ---------------------------------------------------------------------------
// Merged conversion kernel (unchanged — proven clean).
// Blocks [0,4096): weight fp32 -> fragment-ordered bf16 tiles via LDS
//   transpose (coalesced f32x4 row reads).
// Blocks [4096,4608): x fp32 -> 512 pre-tiled swizzled bf16 images.
// ---------------------------------------------------------------------------
__global__ __launch_bounds__(256) void convert_all(
        const float* __restrict__ x, const float* __restrict__ W,
        bf16* __restrict__ xt, bf16* __restrict__ wt) {
    __shared__ float Ls[64][65];       // pad 65: read phase is 2-way (free)
    int t = threadIdx.x;
    int bid = blockIdx.x;
    if (bid < 4096) {
        int nblk = bid >> 8, ne = (bid >> 4) & 15, ks = bid & 15;
        int kb = ne * 1024 + ks * 64;
        int n0 = nblk * 64;
#pragma unroll
        for (int r = 0; r < 4; r++) {
            int idx = r * 256 + t;             // 1024 f32x4 = 64x64 tile
            int row = idx >> 4, c4 = (idx & 15) * 4;
            f32x4 v = *(const f32x4*)(W + (size_t)(kb + row) * OUT_DIM + n0 + c4);
#pragma unroll
            for (int j = 0; j < 4; j++) Ls[row][c4 + j] = v[j];
        }
        __syncthreads();
#pragma unroll
        for (int r = 0; r < 2; r++) {
            int c = r * 256 + t;               // 0..511
            int sub = c >> 6, l = c & 63;
            int lr = l & 15, lq = l >> 4;
            int kk = sub >> 2, wn = (sub >> 1) & 1, nt = sub & 1;
            int krow = kk * 32 + lq * 8;
            int col = wn * 32 + nt * 16 + lr;
            bf16x8 v;
#pragma unroll
            for (int j = 0; j < 8; j++) v[j] = (bf16)Ls[krow + j][col];
            *(bf16x8*)(wt + (size_t)bid * 4096 + c * 8) = v;
        }
    } else {
        int tile = bid - 4096;                 // 512
        int mblk = tile >> 4, ks = tile & 15;
#pragma unroll
        for (int r = 0; r < 4; r++) {
            int q = r * 256 + t;
            int m_loc = q >> 3, sc = q & 7;
            int cc = sc ^ (m_loc & 7);
            const float* src = x + (size_t)(mblk * 128 + m_loc) * IN_DIM + ks * 64 + cc * 8;
            f32x4 a = *(const f32x4*)src;
            f32x4 b = *(const f32x4*)(src + 4);
            bf16x8 v;
#pragma unroll
            for (int j = 0; j < 4; j++) { v[j] = (bf16)a[j]; v[4 + j] = (bf16)b[j]; }
            *(bf16x8*)(xt + (size_t)tile * 8192 + q * 8) = v;
        }
    }
}

// ---------------------------------------------------------------------------
// GEMM, TRANSPOSED compute (verified in R5): p = mfma(B_frag, A_frag, ·)
// gives D = (x·W)^T; D col (lane&15) = batch row, so the combine scale
// cw[b][ne] depends only on (lr, mt, ne).
// R6 change vs R5: scales live in LDS (cwS[128][20], pad 20 -> aligned
// b128 + 2-way/broadcast-only banks), fetched as a 4-expert group
// sg[mt] = ds_read_b128 at each ne%4==0 (16 VGPRs live for 4 ne's) instead
// of a persistent 64-VGPR file (R5 spilled it: +420MB FETCH, +62MB WRITE,
// one reload per ks). Scale LDS traffic: 512 -> 128 b128/CU/ks vs R4.
// Loop/barrier shape = R4/R5 proven-clean: 4 B-buffers, prefetch pair
// {ne+2,ne+3} before computing pair {ne,ne+1}, __syncthreads per pair.
// Block 128m x 64n, 4 waves (2x2), wave tile 64x32, mfma 16x16x32 bf16.
// LDS 58 KB; grid 512 = 2 blocks/CU (grid-limited).
// ---------------------------------------------------------------------------
__global__ __launch_bounds__(256, 2) void moe_gemm(
        const float* __restrict__ cw, const float* __restrict__ bias,
        const bf16* __restrict__ xt, const bf16* __restrict__ wt,
        float* __restrict__ out) {
    int nblk = blockIdx.x;                 // 16 -> bid%8 clusters nblk per XCD
    int mblk = blockIdx.y;                 // 32
    int m0 = mblk * 128, n0 = nblk * 64;
    int t = threadIdx.x;
    int lane = t & 63, w = t >> 6;
    int wm = w >> 1, wn = w & 1;
    int lq = lane >> 4, lr = lane & 15;

    __shared__ bf16 As[128 * 64];          // 16 KB swizzled A image
    __shared__ bf16 Bs[4][64 * 64];        // 4 x 8 KB fragment-ordered B tiles
    __shared__ float cwS[128][20];         // cwS[row_loc][ne], pad 20

    // fill scale table: coalesced f32x4 global loads, aligned b128 LDS writes
#pragma unroll
    for (int r = 0; r < 2; r++) {
        int q = r * 256 + t;               // 512 f32x4 = 2048 floats
        f32x4 v = *(const f32x4*)(cw + (size_t)m0 * NEXP + q * 4);
        *(f32x4*)&cwS[q >> 2][(q & 3) * 4] = v;
    }

    const f32x4 fz = {0.f, 0.f, 0.f, 0.f};
    f32x4 acc[4][2];
#pragma unroll
    for (int mt = 0; mt < 4; mt++)
#pragma unroll
        for (int nt = 0; nt < 2; nt++) acc[mt][nt] = fz;

    int swz = lr & 7;
    int mrow[4];
#pragma unroll
    for (int mt = 0; mt < 4; mt++) mrow[mt] = (wm * 64 + mt * 16 + lr) * 64;

    const bf16* abase = xt + (size_t)(mblk * 16) * 8192;
    const bf16* bbase = wt + (size_t)nblk * (16 * 16 * 4096);

#pragma unroll 1
    for (int ks = 0; ks < 16; ks++) {
        // stage A tile (16 KB) + B tiles for ne=0,1; one drain barrier
        // (the ks=0 barrier also publishes cwS)
        const bf16* asrc = abase + (size_t)ks * 8192 + t * 8;
#pragma unroll
        for (int r = 0; r < 4; r++) gld_lds16(asrc + r * 2048, &As[r * 2048 + t * 8]);
        const bf16* b0 = bbase + (size_t)ks * 4096 + t * 8;          // ne = 0
        gld_lds16(b0,        &Bs[0][t * 8]);
        gld_lds16(b0 + 2048, &Bs[0][2048 + t * 8]);
        const bf16* b1 = bbase + (size_t)(16 + ks) * 4096 + t * 8;   // ne = 1
        gld_lds16(b1,        &Bs[1][t * 8]);
        gld_lds16(b1 + 2048, &Bs[1][2048 + t * 8]);
        __syncthreads();

        // A fragments -> registers, reused across all 16 experts
        bf16x8 af[4][2];
#pragma unroll
        for (int kk = 0; kk < 2; kk++)
#pragma unroll
            for (int mt = 0; mt < 4; mt++)
                af[mt][kk] = *(const bf16x8*)&As[mrow[mt] + ((kk * 4 + lq) ^ swz) * 8];

        f32x4 sg[4];                       // 4-expert scale group (16 VGPRs)
#pragma unroll
        for (int ne = 0; ne < 16; ne++) {
            if ((ne & 3) == 0) {           // refresh scales for ne..ne+3
#pragma unroll
                for (int mt = 0; mt < 4; mt++)
                    sg[mt] = *(const f32x4*)&cwS[wm * 64 + mt * 16 + lr][ne];
            }
            if ((ne & 1) == 0 && ne < 14) {    // prefetch pair {ne+2, ne+3}
                const bf16* bn2 = bbase + (size_t)((ne + 2) * 16 + ks) * 4096 + t * 8;
                bf16* bd2 = &Bs[(ne + 2) & 3][t * 8];
                gld_lds16(bn2,        bd2);
                gld_lds16(bn2 + 2048, bd2 + 2048);
                const bf16* bn3 = bbase + (size_t)((ne + 3) * 16 + ks) * 4096 + t * 8;
                bf16* bd3 = &Bs[(ne + 3) & 3][t * 8];
                gld_lds16(bn3,        bd3);
                gld_lds16(bn3 + 2048, bd3 + 2048);
            }
            // B fragments (linear, conflict-free)
            bf16x8 bfr[2][2];
#pragma unroll
            for (int kk = 0; kk < 2; kk++)
#pragma unroll
                for (int nt = 0; nt < 2; nt++)
                    bfr[kk][nt] = *(const bf16x8*)
                        &Bs[ne & 3][((kk * 2 + wn) * 2 + nt) * 512 + lane * 8];
            // MFMA (swapped operands -> transposed D) + scalar-scale fold
#pragma unroll
            for (int mt = 0; mt < 4; mt++) {
                float sv = sg[mt][ne & 3];          // compile-time extract
#pragma unroll
                for (int nt = 0; nt < 2; nt++) {
                    f32x4 p = __builtin_amdgcn_mfma_f32_16x16x32_bf16(
                        bfr[0][nt], af[mt][0], fz, 0, 0, 0);
                    p = __builtin_amdgcn_mfma_f32_16x16x32_bf16(
                        bfr[1][nt], af[mt][1], p, 0, 0, 0);
                    acc[mt][nt] += sv * p;
                }
            }
            if (ne & 1) __syncthreads();       // barrier per expert pair
        }
    }

    // ---- bias: one MFMA k-step (k = ne), swapped operands like the body ----
    {
        bf16x8 acw[4];
#pragma unroll
        for (int mt = 0; mt < 4; mt++) {
            bf16x8 v;
#pragma unroll
            for (int j = 0; j < 8; j++) v[j] = (bf16)0.f;
            if (lq < 2) {                  // k = lq*8+j in 0..15 real, else 0
                int row = m0 + wm * 64 + mt * 16 + lr;
                f32x4 a = *(const f32x4*)(cw + (size_t)row * NEXP + lq * 8);
                f32x4 b = *(const f32x4*)(cw + (size_t)row * NEXP + lq * 8 + 4);
#pragma unroll
                for (int j = 0; j < 4; j++) { v[j] = (bf16)a[j]; v[4 + j] = (bf16)b[j]; }
            }
            acw[mt] = v;
        }
        bf16x8 bb[2];
#pragma unroll
        for (int nt = 0; nt < 2; nt++) {
            bf16x8 v;
#pragma unroll
            for (int j = 0; j < 8; j++) v[j] = (bf16)0.f;
            if (lq < 2) {
                int col = n0 + wn * 32 + nt * 16 + lr;
#pragma unroll
                for (int j = 0; j < 8; j++)
                    v[j] = (bf16)bias[(size_t)(lq * 8 + j) * OUT_DIM + col];
            }
            bb[nt] = v;
        }
#pragma unroll
        for (int mt = 0; mt < 4; mt++)
#pragma unroll
            for (int nt = 0; nt < 2; nt++)
                acc[mt][nt] = __builtin_amdgcn_mfma_f32_16x16x32_bf16(
                    bb[nt], acw[mt], acc[mt][nt], 0, 0, 0);
    }

    // epilogue: relu + store. Transposed C/D: lane's 4 acc floats are 4
    // CONSECUTIVE output columns -> one dwordx4 store per (mt,nt).
    //   row = m0 + wm*64 + mt*16 + lr;  col = n0 + wn*32 + nt*16 + lq*4 + r2
#pragma unroll
    for (int mt = 0; mt < 4; mt++) {
        int row = m0 + wm * 64 + mt * 16 + lr;
#pragma unroll
        for (int nt = 0; nt < 2; nt++) {
            int col = n0 + wn * 32 + nt * 16 + lq * 4;
            f32x4 v = acc[mt][nt];
#pragma unroll
            for (int r2 = 0; r2 < 4; r2++) v[r2] = v[r2] > 0.f ? v[r2] : 0.f;
            *(f32x4*)(out + (size_t)row * OUT_DIM + col) = v;
        }
    }
}

// ---------------------------------------------------------------------------
// Insurance fallback if ws_size is too small.
// ---------------------------------------------------------------------------
__global__ void fallback_kernel(const float* __restrict__ x, const float* __restrict__ cw,
                                const float* __restrict__ W, const float* __restrict__ bias,
                                float* __restrict__ out) {
    int o = blockIdx.x * 256 + threadIdx.x;
    int b = o >> 10, oc = o & 1023;
    const float* xr = x + (size_t)b * IN_DIM;
    float accv = 0.f;
    for (int n = 0; n < NEXP; n++) {
        const float* wr = W + (size_t)n * IN_DIM * OUT_DIM + oc;
        float z = 0.f;
        for (int i = 0; i < IN_DIM; i++) z += xr[i] * wr[(size_t)i * OUT_DIM];
        accv += cw[(size_t)b * NEXP + n] * (z + bias[n * OUT_DIM + oc]);
    }
    out[o] = accv > 0.f ? accv : 0.f;
}

extern "C" void kernel_launch(void* const* d_in, const int* in_sizes, int n_in,
                              void* d_out, int out_size, void* d_ws, size_t ws_size,
                              hipStream_t stream) {
    const float* x    = (const float*)d_in[0];
    const float* cw   = (const float*)d_in[1];
    const float* W    = (const float*)d_in[2];
    const float* bias = (const float*)d_in[3];
    float* out = (float*)d_out;

    const size_t wt_elems = (size_t)NEXP * IN_DIM * OUT_DIM;   // 32 MB bf16
    const size_t xt_elems = (size_t)BATCH * IN_DIM;            // 8 MB bf16
    if (ws_size < (wt_elems + xt_elems) * sizeof(bf16)) {
        fallback_kernel<<<(BATCH * OUT_DIM) / 256, 256, 0, stream>>>(x, cw, W, bias, out);
        return;
    }
    bf16* wt = (bf16*)d_ws;
    bf16* xt = wt + wt_elems;

    convert_all<<<4096 + 512, 256, 0, stream>>>(x, W, xt, wt);
    moe_gemm<<<dim3(16, 32), 256, 0, stream>>>(cw, bias, xt, wt, out);
}